// Round 1
// baseline (735.576 us; speedup 1.0000x reference)
//
#include <hip/hip_runtime.h>

#define N_IN   100000
#define N_OUT  200000
#define C_IN   128
#define C_OUT  64
#define NK     27
#define MM     100000
#define BN_EPS 1e-5f

#define TILE_M 128
#define APAD   136   // row stride in bf16 elems: 272B = 16B-aligned, +4-dword bank skew

typedef short bf16x8 __attribute__((ext_vector_type(8)));
typedef float f32x4  __attribute__((ext_vector_type(4)));

__device__ __forceinline__ unsigned pack2_bf16(float a, float b) {
  unsigned ua = __float_as_uint(a);
  unsigned ub = __float_as_uint(b);
  ua = (ua + 0x7FFFu + ((ua >> 16) & 1u)) >> 16;          // low half
  ub = (ub + 0x7FFFu + ((ub >> 16) & 1u)) & 0xFFFF0000u;  // high half
  return ua | ub;
}

// weight [k][ci][co] f32  ->  wt [k][co][ci] bf16 (packed pairs along ci)
__global__ void convert_wt_kernel(const float* __restrict__ w, unsigned* __restrict__ wt) {
  int pidx = blockIdx.x * 256 + threadIdx.x;   // 0 .. 27*64*64-1
  int k   = pidx >> 12;
  int rem = pidx & 4095;
  int co  = rem >> 6;
  int ci0 = (rem & 63) * 2;
  const float* wk = w + (size_t)k * C_IN * C_OUT;
  float a = wk[ci0 * C_OUT + co];
  float b = wk[(ci0 + 1) * C_OUT + co];
  wt[pidx] = pack2_bf16(a, b);
}

__global__ __launch_bounds__(256) void scatter_kernel(
    const float* __restrict__ x,
    const unsigned short* __restrict__ wt,
    const int* __restrict__ in_map,
    const int* __restrict__ out_map,
    float* __restrict__ out)
{
  __shared__ unsigned short Als[TILE_M * APAD];
  __shared__ unsigned short Bls[C_OUT * APAD];
  __shared__ int om[TILE_M];

  const int t = threadIdx.x;
  const int k = blockIdx.y;
  const int mbase = blockIdx.x * TILE_M;

  // stage out_map tile
  if (t < TILE_M) {
    int m = mbase + t;
    om[t] = (m < MM) ? out_map[k * MM + m] : 0;
  }

  // stage weight tile [co][ci] bf16, 16B chunks, coalesced
  {
    const uint4* src = (const uint4*)(wt + (size_t)k * C_OUT * C_IN);
    #pragma unroll
    for (int i = 0; i < 4; ++i) {
      int ch  = t + i * 256;        // 0..1023, chunk of 8 bf16
      int co  = ch >> 4;
      int ci0 = (ch & 15) * 8;
      *(uint4*)&Bls[co * APAD + ci0] = src[ch];
    }
  }

  // gather x rows, convert f32->bf16 into LDS
  {
    int r    = t >> 1;
    int half = t & 1;
    int m    = mbase + r;
    int src  = (m < MM) ? in_map[k * MM + m] : 0;
    const float4* xr = (const float4*)(x + (size_t)src * C_IN) + half * 16;
    uint2* dst = (uint2*)&Als[r * APAD + half * 64];
    #pragma unroll
    for (int j = 0; j < 16; ++j) {
      float4 v = xr[j];
      dst[j] = make_uint2(pack2_bf16(v.x, v.y), pack2_bf16(v.z, v.w));
    }
  }
  __syncthreads();

  const int wave = t >> 6;
  const int lane = t & 63;
  const int quad = lane >> 4;
  const int l15  = lane & 15;
  const int rb   = wave * 32;   // this wave's 32 pair-rows

  f32x4 acc[2][4];
  #pragma unroll
  for (int i = 0; i < 2; ++i)
    #pragma unroll
    for (int j = 0; j < 4; ++j)
      acc[i][j] = (f32x4){0.f, 0.f, 0.f, 0.f};

  #pragma unroll
  for (int kk = 0; kk < 4; ++kk) {
    const int koff = kk * 32 + quad * 8;
    bf16x8 a0 = *(const bf16x8*)&Als[(rb + l15) * APAD + koff];
    bf16x8 a1 = *(const bf16x8*)&Als[(rb + 16 + l15) * APAD + koff];
    bf16x8 b0 = *(const bf16x8*)&Bls[(l15) * APAD + koff];
    bf16x8 b1 = *(const bf16x8*)&Bls[(16 + l15) * APAD + koff];
    bf16x8 b2 = *(const bf16x8*)&Bls[(32 + l15) * APAD + koff];
    bf16x8 b3 = *(const bf16x8*)&Bls[(48 + l15) * APAD + koff];
    acc[0][0] = __builtin_amdgcn_mfma_f32_16x16x32_bf16(a0, b0, acc[0][0], 0, 0, 0);
    acc[0][1] = __builtin_amdgcn_mfma_f32_16x16x32_bf16(a0, b1, acc[0][1], 0, 0, 0);
    acc[0][2] = __builtin_amdgcn_mfma_f32_16x16x32_bf16(a0, b2, acc[0][2], 0, 0, 0);
    acc[0][3] = __builtin_amdgcn_mfma_f32_16x16x32_bf16(a0, b3, acc[0][3], 0, 0, 0);
    acc[1][0] = __builtin_amdgcn_mfma_f32_16x16x32_bf16(a1, b0, acc[1][0], 0, 0, 0);
    acc[1][1] = __builtin_amdgcn_mfma_f32_16x16x32_bf16(a1, b1, acc[1][1], 0, 0, 0);
    acc[1][2] = __builtin_amdgcn_mfma_f32_16x16x32_bf16(a1, b2, acc[1][2], 0, 0, 0);
    acc[1][3] = __builtin_amdgcn_mfma_f32_16x16x32_bf16(a1, b3, acc[1][3], 0, 0, 0);
  }

  // scatter-add: C/D layout col=lane&15, row=quad*4+reg
  #pragma unroll
  for (int rt = 0; rt < 2; ++rt) {
    int rloc = rb + rt * 16 + quad * 4;
    int4 o4 = *(const int4*)&om[rloc];
    int mrow = mbase + rloc;
    #pragma unroll
    for (int ct = 0; ct < 4; ++ct) {
      f32x4 v = acc[rt][ct];
      int col = ct * 16 + l15;
      if (mrow + 0 < MM) unsafeAtomicAdd(&out[(size_t)o4.x * C_OUT + col], v[0]);
      if (mrow + 1 < MM) unsafeAtomicAdd(&out[(size_t)o4.y * C_OUT + col], v[1]);
      if (mrow + 2 < MM) unsafeAtomicAdd(&out[(size_t)o4.z * C_OUT + col], v[2]);
      if (mrow + 3 < MM) unsafeAtomicAdd(&out[(size_t)o4.w * C_OUT + col], v[3]);
    }
  }
}

__global__ void stats_kernel(const float* __restrict__ out, float* __restrict__ ws) {
  __shared__ float ls[4][64];
  __shared__ float ls2[4][64];
  int t = threadIdx.x;
  int c = t & 63, sub = t >> 6;
  float s = 0.f, s2 = 0.f;
  for (int r = blockIdx.x * 4 + sub; r < N_OUT; r += gridDim.x * 4) {
    float v = out[(size_t)r * C_OUT + c];
    s += v; s2 += v * v;
  }
  ls[sub][c] = s; ls2[sub][c] = s2;
  __syncthreads();
  if (t < 64) {
    float ts = ls[0][t] + ls[1][t] + ls[2][t] + ls[3][t];
    float t2 = ls2[0][t] + ls2[1][t] + ls2[2][t] + ls2[3][t];
    unsafeAtomicAdd(&ws[t], ts);
    unsafeAtomicAdd(&ws[64 + t], t2);
  }
}

__global__ void prep_kernel(float* __restrict__ ws,
                            const float* __restrict__ gamma,
                            const float* __restrict__ beta) {
  int c = threadIdx.x;
  float mean = ws[c] * (1.0f / N_OUT);
  float var  = ws[64 + c] * (1.0f / N_OUT) - mean * mean;
  var = fmaxf(var, 0.0f);
  float sc = gamma[c] * rsqrtf(var + BN_EPS);
  ws[128 + c] = sc;
  ws[192 + c] = beta[c] - mean * sc;
}

__global__ void finalize_kernel(float* __restrict__ out, const float* __restrict__ ws) {
  int i = blockIdx.x * 256 + threadIdx.x;    // float4 index, exactly 3.2M launched
  float4 v = ((const float4*)out)[i];
  int c0 = (i & 15) * 4;
  float s0 = ws[128 + c0], s1 = ws[129 + c0], s2 = ws[130 + c0], s3 = ws[131 + c0];
  float b0 = ws[192 + c0], b1 = ws[193 + c0], b2 = ws[194 + c0], b3 = ws[195 + c0];
  v.x = fmaxf(fmaf(v.x, s0, b0), 0.f);
  v.y = fmaxf(fmaf(v.y, s1, b1), 0.f);
  v.z = fmaxf(fmaf(v.z, s2, b2), 0.f);
  v.w = fmaxf(fmaf(v.w, s3, b3), 0.f);
  ((float4*)out)[i] = v;
}

extern "C" void kernel_launch(void* const* d_in, const int* in_sizes, int n_in,
                              void* d_out, int out_size, void* d_ws, size_t ws_size,
                              hipStream_t stream) {
  const float* x      = (const float*)d_in[0];
  const float* weight = (const float*)d_in[1];
  const float* gamma  = (const float*)d_in[2];
  const float* beta   = (const float*)d_in[3];
  const int* in_map   = (const int*)d_in[4];
  const int* out_map  = (const int*)d_in[5];
  float* out   = (float*)d_out;
  float* stats = (float*)d_ws;                          // 256 floats
  unsigned* wt = (unsigned*)((char*)d_ws + 1024);       // 442 KB bf16 weights

  hipMemsetAsync(d_out, 0, (size_t)N_OUT * C_OUT * sizeof(float), stream);
  hipMemsetAsync(d_ws, 0, 1024, stream);

  convert_wt_kernel<<<432, 256, 0, stream>>>(weight, wt);

  dim3 g((MM + TILE_M - 1) / TILE_M, NK);
  scatter_kernel<<<g, 256, 0, stream>>>(x, (const unsigned short*)wt, in_map, out_map, out);

  stats_kernel<<<512, 256, 0, stream>>>(out, stats);
  prep_kernel<<<1, 64, 0, stream>>>(stats, gamma, beta);
  finalize_kernel<<<(N_OUT * C_OUT / 4 + 255) / 256, 256, 0, stream>>>(out, stats);
}